// Round 1
// baseline (510.563 us; speedup 1.0000x reference)
//
#include <hip/hip_runtime.h>
#include <math.h>

// SANet attention: b=4, c=64, h=w=64 (HW=4096), fp32.
// out[b, 0:64, :]   = content
// out[b, 64:128, q] = sum_k Fst[b,:,k] * softmax_k(sum_c Fc[b,c,q]*Fs[b,c,k])
//
// Flash-style: block = (batch, 64-row Q tile), online softmax over 64-wide K tiles.
// Rows of the softmax state are wave-private (row q = ty*4+i, ty = lane>>4),
// so m/l updates need no barriers; 3 barriers per K-tile total.

#define Bb 4
#define Cc 64
#define HWs 4096
#define TQ 64
#define TK 64
#define PAD 4   // row stride 68 floats: keeps float4 alignment (68%4==0)

__global__ __launch_bounds__(256) void copy_content_k(const float4* __restrict__ content,
                                                      float4* __restrict__ out) {
    int idx4 = blockIdx.x * 256 + threadIdx.x;      // over 262144 float4
    int b = idx4 >> 16;                             // / 65536
    int rem = idx4 & 65535;
    out[(size_t)b * 131072 + rem] = content[idx4];  // first half of each batch's channels
}

__global__ __launch_bounds__(256) void sanet_attn_k(const float* __restrict__ Fc,
                                                    const float* __restrict__ Fs,
                                                    const float* __restrict__ Fst,
                                                    float* __restrict__ out) {
    const int t  = threadIdx.x;
    const int ty = t >> 4;   // 0..15 -> q rows ty*4..ty*4+3
    const int tx = t & 15;   // 0..15 -> k cols / c cols tx*4..tx*4+3
    const int b  = blockIdx.x >> 6;          // / 64 q-tiles
    const int q0 = (blockIdx.x & 63) * TQ;

    __shared__ float Qs[Cc][TQ + PAD];    // Q[c][q]
    __shared__ float KS[Cc][TK + PAD];    // K[c][k] during S; P[q][k] after barrier
    __shared__ float VsT[TK][Cc + PAD];   // V[k][c]
    __shared__ float m_s[TQ];
    __shared__ float l_s[TQ];

    const float* Fc_b  = Fc  + (size_t)b * Cc * HWs;
    const float* Fs_b  = Fs  + (size_t)b * Cc * HWs;
    const float* Fst_b = Fst + (size_t)b * Cc * HWs;

    // Load Q tile: Qs[c][q] = Fc[b, c, q0+q]  (coalesced float4)
    #pragma unroll
    for (int r = 0; r < 4; ++r) {
        int idx4 = r * 256 + t;          // 0..1023
        int c  = idx4 >> 4;              // 0..63
        int q4 = idx4 & 15;              // 0..15
        *(float4*)&Qs[c][q4 * 4] = *(const float4*)(Fc_b + (size_t)c * HWs + q0 + q4 * 4);
    }
    if (t < TQ) { m_s[t] = -INFINITY; l_s[t] = 0.0f; }

    float acc[4][4];
    #pragma unroll
    for (int i = 0; i < 4; ++i)
        #pragma unroll
        for (int j = 0; j < 4; ++j) acc[i][j] = 0.0f;

    for (int k0 = 0; k0 < HWs; k0 += TK) {
        // ---- load K and V tiles ----
        #pragma unroll
        for (int r = 0; r < 4; ++r) {
            int idx4 = r * 256 + t;
            int c  = idx4 >> 4;
            int k4 = idx4 & 15;
            float4 kv = *(const float4*)(Fs_b + (size_t)c * HWs + k0 + k4 * 4);
            *(float4*)&KS[c][k4 * 4] = kv;
            float4 vv = *(const float4*)(Fst_b + (size_t)c * HWs + k0 + k4 * 4);
            VsT[k4 * 4 + 0][c] = vv.x;
            VsT[k4 * 4 + 1][c] = vv.y;
            VsT[k4 * 4 + 2][c] = vv.z;
            VsT[k4 * 4 + 3][c] = vv.w;
        }
        __syncthreads();   // (A) tiles visible; also protects prior iter's readers

        // ---- S tile: s[i][j] = sum_c Q[c][q=ty*4+i] * K[c][k=tx*4+j] ----
        float s[4][4];
        #pragma unroll
        for (int i = 0; i < 4; ++i)
            #pragma unroll
            for (int j = 0; j < 4; ++j) s[i][j] = 0.0f;
        #pragma unroll 8
        for (int c = 0; c < Cc; ++c) {
            float4 a4 = *(const float4*)&Qs[c][ty * 4];
            float4 b4 = *(const float4*)&KS[c][tx * 4];
            float av[4] = {a4.x, a4.y, a4.z, a4.w};
            float bv[4] = {b4.x, b4.y, b4.z, b4.w};
            #pragma unroll
            for (int i = 0; i < 4; ++i)
                #pragma unroll
                for (int j = 0; j < 4; ++j) s[i][j] += av[i] * bv[j];
        }

        // ---- online softmax stats (wave-local: rows ty*4+i live in this wave) ----
        float alpha_r[4];
        #pragma unroll
        for (int i = 0; i < 4; ++i) {
            float mx = fmaxf(fmaxf(s[i][0], s[i][1]), fmaxf(s[i][2], s[i][3]));
            mx = fmaxf(mx, __shfl_xor(mx, 1));
            mx = fmaxf(mx, __shfl_xor(mx, 2));
            mx = fmaxf(mx, __shfl_xor(mx, 4));
            mx = fmaxf(mx, __shfl_xor(mx, 8));
            const int row = ty * 4 + i;
            float m_old = m_s[row];
            float m_new = fmaxf(m_old, mx);
            float al = __expf(m_old - m_new);   // exp(-inf)=0 on first tile
            float ps = 0.0f;
            #pragma unroll
            for (int j = 0; j < 4; ++j) {
                float e = __expf(s[i][j] - m_new);
                s[i][j] = e;
                ps += e;
            }
            ps += __shfl_xor(ps, 1);
            ps += __shfl_xor(ps, 2);
            ps += __shfl_xor(ps, 4);
            ps += __shfl_xor(ps, 8);
            if (tx == 0) { m_s[row] = m_new; l_s[row] = l_s[row] * al + ps; }
            alpha_r[i] = al;
        }

        __syncthreads();   // (B) everyone done reading KS as K; reuse as P
        #pragma unroll
        for (int i = 0; i < 4; ++i) {
            float4 pv = make_float4(s[i][0], s[i][1], s[i][2], s[i][3]);
            *(float4*)&KS[ty * 4 + i][tx * 4] = pv;   // P[q][k]
        }
        // P rows ty*4+i written & read by the SAME wave -> no barrier needed.

        // ---- O update: acc[i][j] (q=ty*4+i, c=tx*4+j) ----
        #pragma unroll
        for (int i = 0; i < 4; ++i)
            #pragma unroll
            for (int j = 0; j < 4; ++j) acc[i][j] *= alpha_r[i];
        #pragma unroll 4
        for (int kk = 0; kk < TK; kk += 4) {
            float4 p4[4];
            #pragma unroll
            for (int i = 0; i < 4; ++i) p4[i] = *(const float4*)&KS[ty * 4 + i][kk];
            #pragma unroll
            for (int e = 0; e < 4; ++e) {
                float4 v4 = *(const float4*)&VsT[kk + e][tx * 4];
                float pe[4] = {p4[0].x, p4[1].x, p4[2].x, p4[3].x};
                float pv0, pv1, pv2, pv3;
                if (e == 0) { pv0 = p4[0].x; pv1 = p4[1].x; pv2 = p4[2].x; pv3 = p4[3].x; }
                else if (e == 1) { pv0 = p4[0].y; pv1 = p4[1].y; pv2 = p4[2].y; pv3 = p4[3].y; }
                else if (e == 2) { pv0 = p4[0].z; pv1 = p4[1].z; pv2 = p4[2].z; pv3 = p4[3].z; }
                else { pv0 = p4[0].w; pv1 = p4[1].w; pv2 = p4[2].w; pv3 = p4[3].w; }
                (void)pe;
                float vv[4] = {v4.x, v4.y, v4.z, v4.w};
                float pv[4] = {pv0, pv1, pv2, pv3};
                #pragma unroll
                for (int i = 0; i < 4; ++i)
                    #pragma unroll
                    for (int j = 0; j < 4; ++j) acc[i][j] += pv[i] * vv[j];
            }
        }
        __syncthreads();   // (C) before next iter overwrites KS/VsT
    }

    // ---- epilogue: O[c][q] = acc / l, transpose through LDS for coalesced store ----
    float linv[4];
    #pragma unroll
    for (int i = 0; i < 4; ++i) linv[i] = 1.0f / l_s[ty * 4 + i];
    #pragma unroll
    for (int i = 0; i < 4; ++i)
        #pragma unroll
        for (int j = 0; j < 4; ++j)
            Qs[tx * 4 + j][ty * 4 + i] = acc[i][j] * linv[i];   // reuse Qs as O[c][q]
    __syncthreads();
    float* out_b = out + (size_t)b * (2 * Cc * HWs) + (size_t)Cc * HWs + q0;
    #pragma unroll
    for (int r = 0; r < 4; ++r) {
        int idx4 = r * 256 + t;
        int c  = idx4 >> 4;
        int q4 = idx4 & 15;
        *(float4*)(out_b + (size_t)c * HWs + q4 * 4) = *(const float4*)&Qs[c][q4 * 4];
    }
}

extern "C" void kernel_launch(void* const* d_in, const int* in_sizes, int n_in,
                              void* d_out, int out_size, void* d_ws, size_t ws_size,
                              hipStream_t stream) {
    const float* content   = (const float*)d_in[0];
    const float* content_s = (const float*)d_in[1];
    const float* style     = (const float*)d_in[2];
    float* out = (float*)d_out;

    copy_content_k<<<dim3(1024), dim3(256), 0, stream>>>((const float4*)content, (float4*)out);
    sanet_attn_k<<<dim3(Bb * (HWs / TQ)), dim3(256), 0, stream>>>(content, content_s, style, out);
}

// Round 2
// 181.848 us; speedup vs baseline: 2.8076x; 2.8076x over previous
//
#include <hip/hip_runtime.h>
#include <math.h>

// SANet attention, MFMA flash version. b=4, c=64, HW=4096, fp32 in/out.
// out[b,0:64,:] = content ; out[b,64:128,q] = sum_k Fst[:,k] softmax_k(Fc[:,q].Fs[:,k])
//
// Pre-pass (prep_k): content copy + f16 convert:
//   Qt[b][q][c] = (f16)Fc[b][c][q]   (transposed -> S B-frag reads contiguous)
//   Kt[b][k][c] = (f16)Fs[b][c][k]   (transposed -> S A-frag reads contiguous)
//   Vt[b][c][k] = (f16)Fst[b][c][k]  (natural    -> PV A-frag reads contiguous)
// Main (attn_k): 1 wave per 16 q-rows, grid 1024 (1 wave/SIMD). No barriers in
// the K-loop: K/V frags load direct from global (L2-resident 6 MB), P does a
// wave-private LDS round-trip (C-layout -> A/B-operand layout, per m120).
// mfma_f32_16x16x32_f16: A[m=lane&15][k=quad*8+j], B[k=quad*8+j][n=lane&15],
// D[m=quad*4+reg][n=lane&15]  (quad = lane>>4).
// S-mfma computes S^T tile: m=k_key, n=q. PV computes O^T: m=c, n=q.

#define Bb 4
#define Cc 64
#define HWs 4096
#define BATCH_E (Bb == 4 ? 262144 : 0)   // HWs*Cc elements per batch array

typedef _Float16 half8 __attribute__((ext_vector_type(8)));
typedef _Float16 half4 __attribute__((ext_vector_type(4)));
typedef float floatx4 __attribute__((ext_vector_type(4)));

__global__ __launch_bounds__(256) void prep_k(const float* __restrict__ content,
                                              const float* __restrict__ Fc,
                                              const float* __restrict__ Fs,
                                              const float* __restrict__ Fst,
                                              float* __restrict__ out,
                                              _Float16* __restrict__ Qt,
                                              _Float16* __restrict__ Kt,
                                              _Float16* __restrict__ Vt) {
    const int bid = blockIdx.x;
    const int t = threadIdx.x;
    if (bid < 1024) {
        // content copy (float4) + V f16 convert (same linear layout)
        int i4 = bid * 256 + t;                       // 0..262143
        const float4* c4 = (const float4*)content;
        const float4* v4 = (const float4*)Fst;
        float4* o4 = (float4*)out;
        int b = i4 >> 16, rem = i4 & 65535;
        o4[(size_t)b * 131072 + rem] = c4[i4];        // out batch stride 2*64*4096 f32
        float4 v = v4[i4];
        half4 h;
        h[0] = (_Float16)v.x; h[1] = (_Float16)v.y;
        h[2] = (_Float16)v.z; h[3] = (_Float16)v.w;
        *(half4*)(Vt + (size_t)i4 * 4) = h;
    } else {
        // transpose+convert one 64c x 64hw tile of Fc->Qt or Fs->Kt
        __shared__ _Float16 T[64][80];                // hw x c, padded
        int e = bid - 1024;                           // 0..511
        const float* src = (e >> 8) ? Fs : Fc;
        _Float16* dst = (e >> 8) ? Kt : Qt;
        int rem = e & 255;
        int b = rem >> 6;
        int hw0 = (rem & 63) * 64;
        const float* sb = src + (size_t)b * Cc * HWs;
        #pragma unroll
        for (int r = 0; r < 4; ++r) {
            int idx = r * 256 + t;                    // 0..1023
            int c = idx >> 4, x4 = (idx & 15) * 4;
            float4 v = *(const float4*)(sb + (size_t)c * HWs + hw0 + x4);
            T[x4 + 0][c] = (_Float16)v.x;
            T[x4 + 1][c] = (_Float16)v.y;
            T[x4 + 2][c] = (_Float16)v.z;
            T[x4 + 3][c] = (_Float16)v.w;
        }
        __syncthreads();
        _Float16* db = dst + (size_t)b * HWs * Cc;
        #pragma unroll
        for (int r = 0; r < 2; ++r) {
            int idx = r * 256 + t;                    // 0..511
            int row = idx >> 3, g = idx & 7;
            *(half8*)(db + (size_t)(hw0 + row) * Cc + g * 8) = *(half8*)&T[row][g * 8];
        }
    }
}

__device__ __forceinline__ void load_kfr(const _Float16* __restrict__ Kb,
                                         int k0, int l15, int quad, half8 kf[4][2]) {
    #pragma unroll
    for (int m = 0; m < 4; ++m)
        #pragma unroll
        for (int cs = 0; cs < 2; ++cs)
            kf[m][cs] = *(const half8*)(Kb + (size_t)(k0 + m * 16 + l15) * Cc + cs * 32 + quad * 8);
}

__global__ __launch_bounds__(64) void attn_k(const _Float16* __restrict__ Qt,
                                             const _Float16* __restrict__ Kt,
                                             const _Float16* __restrict__ Vt,
                                             float* __restrict__ out) {
    const int lane = threadIdx.x;
    const int quad = lane >> 4;
    const int l15  = lane & 15;
    const int b  = blockIdx.x >> 8;
    const int q0 = (blockIdx.x & 255) * 16;

    __shared__ _Float16 Ps[16][80];   // P^T round-trip buffer, q x k, padded

    const _Float16* Qb = Qt + (size_t)b * HWs * Cc;
    const _Float16* Kb = Kt + (size_t)b * HWs * Cc;
    const _Float16* Vb = Vt + (size_t)b * Cc * HWs;

    // Q B-frags (reused all K-tiles): B[c=quad*8+j][q=l15]
    half8 qf0 = *(const half8*)(Qb + (size_t)(q0 + l15) * Cc + quad * 8);
    half8 qf1 = *(const half8*)(Qb + (size_t)(q0 + l15) * Cc + 32 + quad * 8);

    floatx4 acc[4];
    #pragma unroll
    for (int m = 0; m < 4; ++m) acc[m] = (floatx4)(0.0f);
    float m_run = -INFINITY, l_run = 0.0f;

    half8 ka[4][2], ka2[4][2];
    load_kfr(Kb, 0, l15, quad, ka);

    for (int kt = 0; kt < 64; ++kt) {
        const int k0 = kt * 64;
        // V A-frags for current tile: A[c=m*16+l15][k=ks*32+quad*8+j]
        half8 va[4][2];
        #pragma unroll
        for (int m = 0; m < 4; ++m)
            #pragma unroll
            for (int ks = 0; ks < 2; ++ks)
                va[m][ks] = *(const half8*)(Vb + (size_t)(m * 16 + l15) * HWs + k0 + ks * 32 + quad * 8);
        // prefetch next K-tile A-frags
        load_kfr(Kb, (kt < 63) ? (k0 + 64) : 0, l15, quad, ka2);

        // S^T tile: D[m=k_local][n=q], k_local = msub*16 + quad*4 + reg
        floatx4 s[4];
        #pragma unroll
        for (int m = 0; m < 4; ++m) {
            s[m] = __builtin_amdgcn_mfma_f32_16x16x32_f16(ka[m][0], qf0, (floatx4)(0.0f), 0, 0, 0);
            s[m] = __builtin_amdgcn_mfma_f32_16x16x32_f16(ka[m][1], qf1, s[m], 0, 0, 0);
        }

        // online softmax over k (in-lane 16 values + shfl across quads)
        float mx = -INFINITY;
        #pragma unroll
        for (int m = 0; m < 4; ++m)
            #pragma unroll
            for (int r = 0; r < 4; ++r) mx = fmaxf(mx, s[m][r]);
        mx = fmaxf(mx, __shfl_xor(mx, 16));
        mx = fmaxf(mx, __shfl_xor(mx, 32));
        float m_new = fmaxf(m_run, mx);
        float alpha = __expf(m_run - m_new);          // 0 on first tile
        float ps = 0.0f;
        #pragma unroll
        for (int m = 0; m < 4; ++m)
            #pragma unroll
            for (int r = 0; r < 4; ++r) {
                float e = __expf(s[m][r] - m_new);
                s[m][r] = e;
                ps += e;
            }
        ps += __shfl_xor(ps, 16);
        ps += __shfl_xor(ps, 32);
        l_run = l_run * alpha + ps;
        m_run = m_new;
        #pragma unroll
        for (int m = 0; m < 4; ++m)
            #pragma unroll
            for (int r = 0; r < 4; ++r) acc[m][r] *= alpha;

        // P^T C-layout -> LDS Ps[q][k] (wave-private, no barrier)
        #pragma unroll
        for (int m = 0; m < 4; ++m) {
            half4 p;
            p[0] = (_Float16)s[m][0]; p[1] = (_Float16)s[m][1];
            p[2] = (_Float16)s[m][2]; p[3] = (_Float16)s[m][3];
            *(half4*)&Ps[l15][m * 16 + quad * 4] = p;
        }
        // P B-frags: B[k=ks*32+quad*8+j][q=l15]
        half8 pb0 = *(half8*)&Ps[l15][quad * 8];
        half8 pb1 = *(half8*)&Ps[l15][32 + quad * 8];

        // O^T update: D[m=c][n=q]
        #pragma unroll
        for (int m = 0; m < 4; ++m) {
            acc[m] = __builtin_amdgcn_mfma_f32_16x16x32_f16(va[m][0], pb0, acc[m], 0, 0, 0);
            acc[m] = __builtin_amdgcn_mfma_f32_16x16x32_f16(va[m][1], pb1, acc[m], 0, 0, 0);
        }

        #pragma unroll
        for (int m = 0; m < 4; ++m)
            #pragma unroll
            for (int cs = 0; cs < 2; ++cs) ka[m][cs] = ka2[m][cs];
    }

    // epilogue: out[b][64 + c][q0 + q] = acc / l
    float linv = 1.0f / l_run;                        // l for q = l15
    float* ob = out + (size_t)b * (2 * Cc * HWs) + (size_t)Cc * HWs;
    #pragma unroll
    for (int m = 0; m < 4; ++m)
        #pragma unroll
        for (int r = 0; r < 4; ++r) {
            int c = m * 16 + quad * 4 + r;
            ob[(size_t)c * HWs + q0 + l15] = acc[m][r] * linv;
        }
}

extern "C" void kernel_launch(void* const* d_in, const int* in_sizes, int n_in,
                              void* d_out, int out_size, void* d_ws, size_t ws_size,
                              hipStream_t stream) {
    const float* content   = (const float*)d_in[0];
    const float* content_s = (const float*)d_in[1];
    const float* style     = (const float*)d_in[2];
    float* out = (float*)d_out;

    _Float16* Qt = (_Float16*)d_ws;                   // [4][4096][64]
    _Float16* Kt = Qt + (size_t)Bb * HWs * Cc;        // [4][4096][64]
    _Float16* Vt = Kt + (size_t)Bb * HWs * Cc;        // [4][64][4096]

    prep_k<<<dim3(1536), dim3(256), 0, stream>>>(content, content, content_s, style,
                                                 out, Qt, Kt, Vt);
    attn_k<<<dim3(Bb * (HWs / 16)), dim3(64), 0, stream>>>(Qt, Kt, Vt, out);
}